// Round 6
// baseline (2501.134 us; speedup 1.0000x reference)
//
#include <hip/hip_runtime.h>
#include <math.h>

#define EPSV 1e-5f
#define NSTATB 960

typedef __attribute__((ext_vector_type(8))) short short8;
typedef __attribute__((ext_vector_type(4))) float floatx4;

__device__ __forceinline__ float waveSum(float v) {
#pragma unroll
  for (int off = 32; off > 0; off >>= 1) v += __shfl_xor(v, off, 64);
  return v;
}

__device__ __forceinline__ unsigned bfr(float f) {
  union { float f; unsigned u; } v;
  v.f = f;
  return (v.u + 0x7FFFu + ((v.u >> 16) & 1u)) >> 16;  // round-nearest-even
}

// ---------------------------------------------------------------------------
// Transpose + convert: Wt[n*K + k] = bf16(W[k*N + n])
// ---------------------------------------------------------------------------
__global__ __launch_bounds__(256) void wT_bf16(const float* __restrict__ W,
                                               short* __restrict__ Wt, int K, int N) {
  __shared__ short t[32][33];
  int k0 = blockIdx.x * 32, n0 = blockIdx.y * 32;
  int x = threadIdx.x & 31, y = threadIdx.x >> 5;  // 32 x 8
#pragma unroll
  for (int dy = 0; dy < 32; dy += 8) {
    int k = k0 + y + dy, n = n0 + x;
    t[y + dy][x] = (k < K && n < N) ? (short)bfr(W[(size_t)k * N + n]) : (short)0;
  }
  __syncthreads();
#pragma unroll
  for (int dy = 0; dy < 32; dy += 8) {
    int n = n0 + y + dy, k = k0 + x;
    if (n < N && k < K) Wt[(size_t)n * K + k] = t[x][y + dy];
  }
}

// ---------------------------------------------------------------------------
// MFMA GEMM: Y[m,n] = sum_k bf16(A[row(m),k]) * Wt_bf16[n,k] (+ bias[n])
// row(m) = idx ? idx[m] : m. A fp32 [*,K]; Wt bf16 [N,K]. 128x128 tile, BK=64.
// Per-thread gather tasks are static in tid: row ptrs hoisted to registers
// once (no LDS rowidx reads in the K loop), and next tile's A/B global loads
// are issued BEFORE the compute barrier so gather latency overlaps MFMA.
// Requires: K % 64 == 0, N % 128 == 0, A rows 16B-aligned (K%4==0).
// ---------------------------------------------------------------------------
__global__ __launch_bounds__(256) void gemm_mfma(
    const float* __restrict__ A, const short* __restrict__ Wt,
    const float* __restrict__ bias, float* __restrict__ Y,
    const int* __restrict__ idx, int M, int K, int N) {
  constexpr int LDT = 72;  // padded LDS row stride (shorts): 2-way banks only
  __shared__ short Alds[128 * LDT];
  __shared__ short Blds[128 * LDT];
  int tid = threadIdx.x;
  int m0 = blockIdx.y * 128, n0 = blockIdx.x * 128;

  // --- static per-thread staging tasks -------------------------------------
  // A: thread covers rows rbase+16t (t=0..7), float chunk s (cols 4s..4s+3)
  int s = tid & 15, rbase = tid >> 4;
  const float* aptr[8];
#pragma unroll
  for (int t = 0; t < 8; t++) {
    int row = m0 + rbase + 16 * t;
    int ar = (row < M) ? (idx ? idx[row] : row) : -1;
    aptr[t] = (ar >= 0) ? A + (size_t)ar * K + 4 * s : nullptr;
  }
  // B: thread covers rows bn_+32u (u=0..3), short chunk c8 (k: c8..c8+7)
  int bn_ = tid >> 3, c8 = (tid & 7) * 8;
  const short* bptr[4];
#pragma unroll
  for (int u = 0; u < 4; u++)
    bptr[u] = Wt + (size_t)(n0 + bn_ + 32 * u) * K + c8;

  int wave = tid >> 6, lane = tid & 63;
  int wm = (wave & 1) * 64, wn = (wave >> 1) * 64;
  int lr = lane & 15, quad = lane >> 4;
  floatx4 acc[4][4];
#pragma unroll
  for (int i = 0; i < 4; i++)
#pragma unroll
    for (int j = 0; j < 4; j++) acc[i][j] = (floatx4)0.f;

  float4 pa[8];
  int4 pb[4];
  float4 z4;
  z4.x = z4.y = z4.z = z4.w = 0.f;

  // prologue: load tile k=0 into registers
#pragma unroll
  for (int t = 0; t < 8; t++)
    pa[t] = aptr[t] ? *reinterpret_cast<const float4*>(aptr[t]) : z4;
#pragma unroll
  for (int u = 0; u < 4; u++)
    pb[u] = *reinterpret_cast<const int4*>(bptr[u]);

  for (int k0 = 0; k0 < K; k0 += 64) {
    // write staged registers to LDS
#pragma unroll
    for (int t = 0; t < 8; t++) {
      uint2 p;
      p.x = bfr(pa[t].x) | (bfr(pa[t].y) << 16);
      p.y = bfr(pa[t].z) | (bfr(pa[t].w) << 16);
      *reinterpret_cast<uint2*>(&Alds[(rbase + 16 * t) * LDT + 4 * s]) = p;
    }
#pragma unroll
    for (int u = 0; u < 4; u++)
      *reinterpret_cast<int4*>(&Blds[(bn_ + 32 * u) * LDT + c8]) = pb[u];
    // issue next tile's global loads BEFORE the barrier -> overlap with MFMA
    if (k0 + 64 < K) {
      int kn = k0 + 64;
#pragma unroll
      for (int t = 0; t < 8; t++)
        pa[t] = aptr[t] ? *reinterpret_cast<const float4*>(aptr[t] + kn) : z4;
#pragma unroll
      for (int u = 0; u < 4; u++)
        pb[u] = *reinterpret_cast<const int4*>(bptr[u] + kn);
    }
    __syncthreads();
#pragma unroll
    for (int h = 0; h < 2; h++) {
      short8 af[4], bfv[4];
#pragma unroll
      for (int i = 0; i < 4; i++)
        af[i] = *reinterpret_cast<const short8*>(
            &Alds[(wm + i * 16 + lr) * LDT + h * 32 + quad * 8]);
#pragma unroll
      for (int j = 0; j < 4; j++)
        bfv[j] = *reinterpret_cast<const short8*>(
            &Blds[(wn + j * 16 + lr) * LDT + h * 32 + quad * 8]);
#pragma unroll
      for (int i = 0; i < 4; i++)
#pragma unroll
        for (int j = 0; j < 4; j++)
          acc[i][j] = __builtin_amdgcn_mfma_f32_16x16x32_bf16(af[i], bfv[j],
                                                              acc[i][j], 0, 0, 0);
    }
    __syncthreads();
  }
  // epilogue: C/D layout col=lane&15, row=quad*4+reg
#pragma unroll
  for (int i = 0; i < 4; i++) {
#pragma unroll
    for (int j = 0; j < 4; j++) {
      int n = n0 + wn + j * 16 + lr;
      float bv = bias ? bias[n] : 0.f;
#pragma unroll
      for (int r = 0; r < 4; r++) {
        int m = m0 + wm + i * 16 + quad * 4 + r;
        if (m < M) Y[(size_t)m * N + n] = acc[i][j][r] + bv;
      }
    }
  }
}

// ---------------------------------------------------------------------------
// fp32 fallback GEMM (MLP head, N=153)
// ---------------------------------------------------------------------------
__global__ __launch_bounds__(256) void gemm_bias(
    const float* __restrict__ A, const float* __restrict__ W,
    const float* __restrict__ bias, float* __restrict__ Y,
    const int* __restrict__ idx, int M, int K, int N) {
  __shared__ float As[16][65];
  __shared__ float Bs[16][64];
  int tid = threadIdx.x;
  int tx = tid & 15, ty = tid >> 4;
  int m0 = blockIdx.x * 64, n0 = blockIdx.y * 64;
  float acc[4][4] = {};
  for (int k0 = 0; k0 < K; k0 += 16) {
    for (int l = tid; l < 64 * 16; l += 256) {
      int r = l >> 4, kk = l & 15;
      int row = m0 + r;
      float v = 0.f;
      if (row < M) {
        int ar = idx ? idx[row] : row;
        v = A[(size_t)ar * K + k0 + kk];
      }
      As[kk][r] = v;
    }
    for (int l = tid; l < 16 * 64; l += 256) {
      int kk = l >> 6, n = l & 63;
      int col = n0 + n;
      Bs[kk][n] = (col < N) ? W[(size_t)(k0 + kk) * N + col] : 0.f;
    }
    __syncthreads();
#pragma unroll
    for (int kk = 0; kk < 16; kk++) {
      float a[4], b[4];
#pragma unroll
      for (int i = 0; i < 4; i++) a[i] = As[kk][ty + 16 * i];
#pragma unroll
      for (int j = 0; j < 4; j++) b[j] = Bs[kk][tx + 16 * j];
#pragma unroll
      for (int i = 0; i < 4; i++)
#pragma unroll
        for (int j = 0; j < 4; j++) acc[i][j] += a[i] * b[j];
    }
    __syncthreads();
  }
#pragma unroll
  for (int i = 0; i < 4; i++) {
    int m = m0 + ty + 16 * i;
    if (m >= M) continue;
#pragma unroll
    for (int j = 0; j < 4; j++) {
      int n = n0 + tx + 16 * j;
      if (n < N) Y[(size_t)m * N + n] = acc[i][j] + (bias ? bias[n] : 0.f);
    }
  }
}

// ---------------------------------------------------------------------------
__global__ __launch_bounds__(256) void att_scores(
    const float* __restrict__ x, const float* __restrict__ attS,
    const float* __restrict__ attD, float* __restrict__ a_s,
    float* __restrict__ a_d, int Ns, int Nd) {
  int w = blockIdx.x * 4 + (threadIdx.x >> 6);
  int lane = threadIdx.x & 63;
  int i = w >> 2, h = w & 3;
  if (i >= Ns) return;
  const float* xr = x + (size_t)i * 512 + h * 128;
  float v1 = xr[lane], v2 = xr[lane + 64];
  float s = waveSum(v1 * attS[h * 128 + lane] + v2 * attS[h * 128 + lane + 64]);
  if (lane == 0) a_s[i * 4 + h] = s;
  if (i < Nd) {
    float d = waveSum(v1 * attD[h * 128 + lane] + v2 * attD[h * 128 + lane + 64]);
    if (lane == 0) a_d[i * 4 + h] = d;
  }
}

__global__ void build_starts(const int* __restrict__ dst, int E, int n_dst,
                             int* __restrict__ starts) {
  int k = blockIdx.x * 256 + threadIdx.x;
  if (k > E) return;
  if (k == 0) {
    int d0 = dst[0];
    for (int j = 0; j <= d0; j++) starts[j] = 0;
  } else if (k < E) {
    int d = dst[k], dp = dst[k - 1];
    for (int j = dp + 1; j <= d; j++) starts[j] = k;
  } else {
    int dl = dst[E - 1];
    for (int j = dl + 1; j <= n_dst; j++) starts[j] = E;
  }
}

__global__ void edge_logits(const int* __restrict__ src, const int* __restrict__ dst,
                            const float* __restrict__ a_s, const float* __restrict__ a_d,
                            float* __restrict__ logits, int E) {
  int k = blockIdx.x * 256 + threadIdx.x;
  if (k >= E) return;
  int s = src[k], d = dst[k];
#pragma unroll
  for (int h = 0; h < 4; h++) {
    float v = a_s[s * 4 + h] + a_d[d * 4 + h];
    v = (v >= 0.f) ? v : 0.2f * v;
    logits[k * 4 + h] = v;
  }
}

__global__ void node_ms(const float* __restrict__ logits, const int* __restrict__ starts,
                        float* __restrict__ ms, int n_dst) {
  int t = blockIdx.x * 256 + threadIdx.x;
  int j = t >> 2, h = t & 3;
  if (j >= n_dst) return;
  int r0 = starts[j], r1 = starts[j + 1];
  float m = -1e30f;
  for (int k = r0; k < r1; k++) m = fmaxf(m, logits[k * 4 + h]);
  float s = 0.f;
  for (int k = r0; k < r1; k++) s += __expf(logits[k * 4 + h] - m);
  ms[j * 8 + h] = m;
  ms[j * 8 + 4 + h] = s;
}

__global__ void edge_coef(float* __restrict__ logits, const int* __restrict__ dst,
                          const float* __restrict__ ms, int E) {
  int k = blockIdx.x * 256 + threadIdx.x;
  if (k >= E) return;
  int d = dst[k];
#pragma unroll
  for (int h = 0; h < 4; h++) {
    float m = ms[d * 8 + h], s = ms[d * 8 + 4 + h];
    logits[k * 4 + h] = __expf(logits[k * 4 + h] - m) / fmaxf(s, 1e-16f);
  }
}

__global__ __launch_bounds__(128) void gat_aggregate(
    const float* __restrict__ x, const float* __restrict__ coef,
    const int* __restrict__ src, const int* __restrict__ starts,
    const float* __restrict__ bg, float* __restrict__ o, int n_dst) {
  int j = blockIdx.x;
  int c = threadIdx.x;
  int r0 = starts[j], r1 = starts[j + 1];
  float a0 = 0.f, a1 = 0.f, a2 = 0.f, a3 = 0.f;
  for (int k = r0; k < r1; k++) {
    int s = src[k];
    const float* xr = x + (size_t)s * 512;
    float c0 = coef[k * 4 + 0], c1 = coef[k * 4 + 1];
    float c2 = coef[k * 4 + 2], c3 = coef[k * 4 + 3];
    a0 += c0 * xr[c];
    a1 += c1 * xr[128 + c];
    a2 += c2 * xr[256 + c];
    a3 += c3 * xr[384 + c];
  }
  o[(size_t)j * 128 + c] = 0.25f * (a0 + a1 + a2 + a3) + bg[c];
}

// ---------------------------------------------------------------------------
// BatchNorm stats: 960 partial blocks; finalize = 128 blocks (one channel
// each), wave-reduce over partials. bn_apply fuses activation.
// ---------------------------------------------------------------------------
__global__ __launch_bounds__(128) void bn_partial(const float* __restrict__ x,
                                                  float* __restrict__ partial, int N) {
  int c = threadIdx.x;
  float s = 0.f, ss = 0.f;
  for (int r = blockIdx.x; r < N; r += gridDim.x) {
    float v = x[(size_t)r * 128 + c];
    s += v;
    ss += v * v;
  }
  partial[blockIdx.x * 256 + c] = s;
  partial[blockIdx.x * 256 + 128 + c] = ss;
}

__global__ __launch_bounds__(64) void bn_finalize(const float* __restrict__ partial,
                                                  int G, int N, float* __restrict__ stats) {
  int c = blockIdx.x;      // channel 0..127
  int lane = threadIdx.x;  // 0..63
  float s = 0.f, ss = 0.f;
  for (int b = lane; b < G; b += 64) {
    s += partial[b * 256 + c];
    ss += partial[b * 256 + 128 + c];
  }
  s = waveSum(s);
  ss = waveSum(ss);
  if (lane == 0) {
    float mu = s / (float)N;
    float var = ss / (float)N - mu * mu;
    stats[c] = mu;
    stats[128 + c] = rsqrtf(var + EPSV);
  }
}

__global__ __launch_bounds__(128) void bn_apply(
    const float* __restrict__ x, const float* __restrict__ stats,
    const float* __restrict__ g, const float* __restrict__ b,
    float* __restrict__ y, int M, int ostride, int act) {
  int r = blockIdx.x;
  int c = threadIdx.x;
  if (r >= M) return;
  float v = x[(size_t)r * 128 + c];
  v = (v - stats[c]) * stats[128 + c] * g[c] + b[c];
  if (act == 1) v = (v > 0.f) ? v : (__expf(v) - 1.f);
  if (act == 2) v = fmaxf(v, 0.f);
  y[(size_t)r * ostride + c] = v;
}

__global__ __launch_bounds__(128) void pool_attn(
    const float* __restrict__ temp, const float* __restrict__ wp,
    const float* __restrict__ bp, float* __restrict__ sk, int batch) {
  int b = blockIdx.x, c = threadIdx.x;
  int lane = c & 63, wid = c >> 6;
  __shared__ float red[12];
  const float* tr = temp + (size_t)b * 768;
  float wpc = wp[c];
  float t[6];
#pragma unroll
  for (int p = 0; p < 6; p++) t[p] = tr[p * 128 + c];
#pragma unroll
  for (int p = 0; p < 6; p++) {
    float v = waveSum(t[p] * wpc);
    if (lane == 0) red[wid * 6 + p] = v;
  }
  __syncthreads();
  float z[6], m = -1e30f;
#pragma unroll
  for (int p = 0; p < 6; p++) {
    z[p] = red[p] + red[6 + p] + bp[0];
    m = fmaxf(m, z[p]);
  }
  float es = 0.f;
#pragma unroll
  for (int p = 0; p < 6; p++) {
    z[p] = __expf(z[p] - m);
    es += z[p];
  }
  float inv = 1.f / es;
  float o = 0.f;
#pragma unroll
  for (int p = 0; p < 6; p++) o += z[p] * inv * t[p];
  sk[(size_t)b * 128 + c] = o;
}

// ---------------------------------------------------------------------------
extern "C" void kernel_launch(void* const* d_in, const int* in_sizes, int n_in,
                              void* d_out, int out_size, void* d_ws, size_t ws_size,
                              hipStream_t stream) {
  const float* feature = (const float*)d_in[0];
  const int* nodes_idx[2] = {(const int*)d_in[1], (const int*)d_in[4]};
  const int* edge_src[2] = {(const int*)d_in[2], (const int*)d_in[5]};
  const int* edge_dst[2] = {(const int*)d_in[3], (const int*)d_in[6]};
  const float *Wsk[2], *bsk[2], *bng[2], *bnb[2], *Wg[2], *attS[2], *attD[2],
      *bg[2], *wp[2], *bp[2], *pg[2], *pb[2];
  for (int l = 0; l < 2; l++) {
    int base = 7 + l * 12;
    Wsk[l] = (const float*)d_in[base + 0];
    bsk[l] = (const float*)d_in[base + 1];
    bng[l] = (const float*)d_in[base + 2];
    bnb[l] = (const float*)d_in[base + 3];
    Wg[l] = (const float*)d_in[base + 4];
    attS[l] = (const float*)d_in[base + 5];
    attD[l] = (const float*)d_in[base + 6];
    bg[l] = (const float*)d_in[base + 7];
    wp[l] = (const float*)d_in[base + 8];
    bp[l] = (const float*)d_in[base + 9];
    pg[l] = (const float*)d_in[base + 10];
    pb[l] = (const float*)d_in[base + 11];
  }
  const float* Wm1 = (const float*)d_in[31];
  const float* bm1 = (const float*)d_in[32];
  const float* mg = (const float*)d_in[33];
  const float* mb = (const float*)d_in[34];
  const float* Wm2 = (const float*)d_in[35];
  const float* bm2 = (const float*)d_in[36];

  // ---- workspace layout (float units) ----
  float* ws = (float*)d_ws;
  float* bufG = ws;   ws += 20480000;  // 40000*512 (also skip out 100000*128)
  float* bufO = ws;   ws += 3840000;   // 30000*128
  float* temp = ws;   ws += 19200000;  // 25000*6*128
  float* f0   = ws;   ws += 3200000;   // 25000*128
  float* f1   = ws;   ws += 1024000;   // 8000*128
  float* bufH = ws;   ws += 1024000;   // 8000*128
  float* a_s  = ws;   ws += 160000;    // 40000*4
  float* a_d  = ws;   ws += 120000;    // 30000*4
  float* logi = ws;   ws += 800000;    // 200000*4
  float* ms   = ws;   ws += 240000;    // 30000*8
  float* part = ws;   ws += NSTATB * 256;
  float* stats = ws;  ws += 256;
  int* starts = (int*)ws; ws += 30016; // 30001 ints
  short* wt_sk0 = (short*)ws; ws += 32768;   // 128*512 shorts
  short* wt_g0  = (short*)ws; ws += 655360;  // 5*512*512 shorts
  short* wt_sk1 = (short*)ws; ws += 8192;    // 128*128 shorts
  short* wt_g1  = (short*)ws; ws += 163840;  // 5*512*128 shorts

  auto cdiv = [](int a, int b) { return (a + b - 1) / b; };

  wT_bf16<<<dim3(16, 4), 256, 0, stream>>>(Wsk[0], wt_sk0, 512, 128);
  for (int e2 = 0; e2 < 5; e2++)
    wT_bf16<<<dim3(16, 16), 256, 0, stream>>>(Wg[0] + (size_t)e2 * 512 * 512,
                                              wt_g0 + (size_t)e2 * 512 * 512, 512, 512);
  wT_bf16<<<dim3(4, 4), 256, 0, stream>>>(Wsk[1], wt_sk1, 128, 128);
  for (int e2 = 0; e2 < 5; e2++)
    wT_bf16<<<dim3(4, 16), 256, 0, stream>>>(Wg[1] + (size_t)e2 * 128 * 512,
                                             wt_g1 + (size_t)e2 * 512 * 128, 128, 512);

  auto run_layer = [&](const float* X, int Nf, int din, int li, float* fout,
                       const short* wt_sk, const short* wt_g) {
    const int Nsrc = (li == 0) ? 40000 : 20000;
    const int n_dst = (li == 0) ? 30000 : 10000;
    const int batch = (li == 0) ? 25000 : 8000;
    const int E = (li == 0) ? 200000 : 80000;

    gemm_mfma<<<dim3(1, cdiv(Nf, 128)), 256, 0, stream>>>(
        X, wt_sk, bsk[li], bufG, nullptr, Nf, din, 128);
    bn_partial<<<NSTATB, 128, 0, stream>>>(bufG, part, Nf);
    bn_finalize<<<128, 64, 0, stream>>>(part, NSTATB, Nf, stats);
    bn_apply<<<batch, 128, 0, stream>>>(bufG, stats, bng[li], bnb[li], temp,
                                        batch, 768, 1);

    for (int e2 = 0; e2 < 5; e2++) {
      const int* idx = nodes_idx[li] + (size_t)e2 * Nsrc;
      const int* src = edge_src[li] + (size_t)e2 * E;
      const int* dst = edge_dst[li] + (size_t)e2 * E;
      gemm_mfma<<<dim3(4, cdiv(Nsrc, 128)), 256, 0, stream>>>(
          X, wt_g + (size_t)e2 * din * 512, nullptr, bufG, idx, Nsrc, din, 512);
      att_scores<<<Nsrc, 256, 0, stream>>>(bufG, attS[li] + e2 * 512,
                                           attD[li] + e2 * 512, a_s, a_d, Nsrc, n_dst);
      build_starts<<<cdiv(E + 1, 256), 256, 0, stream>>>(dst, E, n_dst, starts);
      edge_logits<<<cdiv(E, 256), 256, 0, stream>>>(src, dst, a_s, a_d, logi, E);
      node_ms<<<cdiv(n_dst * 4, 256), 256, 0, stream>>>(logi, starts, ms, n_dst);
      edge_coef<<<cdiv(E, 256), 256, 0, stream>>>(logi, dst, ms, E);
      gat_aggregate<<<n_dst, 128, 0, stream>>>(bufG, logi, src, starts,
                                               bg[li] + e2 * 128, bufO, n_dst);
      bn_partial<<<NSTATB, 128, 0, stream>>>(bufO, part, n_dst);
      bn_finalize<<<128, 64, 0, stream>>>(part, NSTATB, n_dst, stats);
      bn_apply<<<batch, 128, 0, stream>>>(bufO, stats, bng[li] + (e2 + 1) * 128,
                                          bnb[li] + (e2 + 1) * 128,
                                          temp + (e2 + 1) * 128, batch, 768, 1);
    }

    pool_attn<<<batch, 128, 0, stream>>>(temp, wp[li], bp[li], bufO, batch);
    bn_partial<<<NSTATB, 128, 0, stream>>>(bufO, part, batch);
    bn_finalize<<<128, 64, 0, stream>>>(part, NSTATB, batch, stats);
    bn_apply<<<batch, 128, 0, stream>>>(bufO, stats, pg[li], pb[li], fout, batch,
                                        128, 0);
  };

  run_layer(feature, 100000, 512, 0, f0, wt_sk0, wt_g0);
  run_layer(f0, 25000, 128, 1, f1, wt_sk1, wt_g1);

  gemm_bias<<<dim3(cdiv(8000, 64), 2), 256, 0, stream>>>(f1, Wm1, bm1, bufG,
                                                         nullptr, 8000, 128, 128);
  bn_partial<<<NSTATB, 128, 0, stream>>>(bufG, part, 8000);
  bn_finalize<<<128, 64, 0, stream>>>(part, NSTATB, 8000, stats);
  bn_apply<<<8000, 128, 0, stream>>>(bufG, stats, mg, mb, bufH, 8000, 128, 2);
  gemm_bias<<<dim3(cdiv(8000, 64), 3), 256, 0, stream>>>(
      bufH, Wm2, bm2, (float*)d_out, nullptr, 8000, 128, 153);
}

// Round 7
// 2451.826 us; speedup vs baseline: 1.0201x; 1.0201x over previous
//
#include <hip/hip_runtime.h>
#include <math.h>

#define EPSV 1e-5f
#define NSTATB 960

typedef __attribute__((ext_vector_type(8))) short short8;
typedef __attribute__((ext_vector_type(4))) float floatx4;

__device__ __forceinline__ float waveSum(float v) {
#pragma unroll
  for (int off = 32; off > 0; off >>= 1) v += __shfl_xor(v, off, 64);
  return v;
}

__device__ __forceinline__ unsigned bfr(float f) {
  union { float f; unsigned u; } v;
  v.f = f;
  return (v.u + 0x7FFFu + ((v.u >> 16) & 1u)) >> 16;  // round-nearest-even
}

// ---------------------------------------------------------------------------
// Transpose + convert: Wt[n*K + k] = bf16(W[k*N + n])
// ---------------------------------------------------------------------------
__global__ __launch_bounds__(256) void wT_bf16(const float* __restrict__ W,
                                               short* __restrict__ Wt, int K, int N) {
  __shared__ short t[32][33];
  int k0 = blockIdx.x * 32, n0 = blockIdx.y * 32;
  int x = threadIdx.x & 31, y = threadIdx.x >> 5;  // 32 x 8
#pragma unroll
  for (int dy = 0; dy < 32; dy += 8) {
    int k = k0 + y + dy, n = n0 + x;
    t[y + dy][x] = (k < K && n < N) ? (short)bfr(W[(size_t)k * N + n]) : (short)0;
  }
  __syncthreads();
#pragma unroll
  for (int dy = 0; dy < 32; dy += 8) {
    int n = n0 + y + dy, k = k0 + x;
    if (n < N && k < K) Wt[(size_t)n * K + k] = t[x][y + dy];
  }
}

// ---------------------------------------------------------------------------
// MFMA GEMM: Y[m,n] = sum_k bf16(A[row(m),k]) * Wt_bf16[n,k] (+ bias[n])
// 128x128 tile, BK=32, register prefetch of next tile issued before the
// compute barrier (latency overlap). Prefetch state kept small (pa[4]+pb[2])
// and __launch_bounds__(256,3) gives a ~170-VGPR budget -> no scratch spill
// (R6 lesson: 96-VGPR target spilled ~250MB/dispatch of scratch traffic).
// Requires: K % 32 == 0, N % 128 == 0, A rows 16B-aligned (K%4==0).
// ---------------------------------------------------------------------------
__global__ __launch_bounds__(256, 3) void gemm_mfma(
    const float* __restrict__ A, const short* __restrict__ Wt,
    const float* __restrict__ bias, float* __restrict__ Y,
    const int* __restrict__ idx, int M, int K, int N) {
  constexpr int LDT = 40;  // padded LDS row stride (shorts)
  __shared__ short Alds[128 * LDT];
  __shared__ short Blds[128 * LDT];
  int tid = threadIdx.x;
  int m0 = blockIdx.y * 128, n0 = blockIdx.x * 128;

  // --- static per-thread staging tasks -------------------------------------
  // A: rows rbase+32t (t=0..3), float4 chunk s (floats 4s..4s+3)
  int s = tid & 7, rbase = tid >> 3;
  const float* aptr[4];
#pragma unroll
  for (int t = 0; t < 4; t++) {
    int row = m0 + rbase + 32 * t;
    int ar = (row < M) ? (idx ? idx[row] : row) : -1;
    aptr[t] = (ar >= 0) ? A + (size_t)ar * K + 4 * s : nullptr;
  }
  // B: rows nb+64u (u=0..1), short chunk c8 (k: c8..c8+7)
  int nb = tid >> 2, c8 = (tid & 3) * 8;
  const short* bptr[2];
#pragma unroll
  for (int u = 0; u < 2; u++)
    bptr[u] = Wt + (size_t)(n0 + nb + 64 * u) * K + c8;

  int wave = tid >> 6, lane = tid & 63;
  int wm = (wave & 1) * 64, wn = (wave >> 1) * 64;
  int lr = lane & 15, quad = lane >> 4;
  floatx4 acc[4][4];
#pragma unroll
  for (int i = 0; i < 4; i++)
#pragma unroll
    for (int j = 0; j < 4; j++) acc[i][j] = (floatx4)0.f;

  float4 pa[4];
  int4 pb[2];
  float4 z4;
  z4.x = z4.y = z4.z = z4.w = 0.f;

  // prologue: load tile k=0 into registers
#pragma unroll
  for (int t = 0; t < 4; t++)
    pa[t] = aptr[t] ? *reinterpret_cast<const float4*>(aptr[t]) : z4;
#pragma unroll
  for (int u = 0; u < 2; u++)
    pb[u] = *reinterpret_cast<const int4*>(bptr[u]);

  for (int k0 = 0; k0 < K; k0 += 32) {
    // write staged registers to LDS
#pragma unroll
    for (int t = 0; t < 4; t++) {
      uint2 p;
      p.x = bfr(pa[t].x) | (bfr(pa[t].y) << 16);
      p.y = bfr(pa[t].z) | (bfr(pa[t].w) << 16);
      *reinterpret_cast<uint2*>(&Alds[(rbase + 32 * t) * LDT + 4 * s]) = p;
    }
#pragma unroll
    for (int u = 0; u < 2; u++)
      *reinterpret_cast<int4*>(&Blds[(nb + 64 * u) * LDT + c8]) = pb[u];
    // issue next tile's global loads BEFORE the barrier -> overlap with MFMA
    if (k0 + 32 < K) {
      int kn = k0 + 32;
#pragma unroll
      for (int t = 0; t < 4; t++)
        pa[t] = aptr[t] ? *reinterpret_cast<const float4*>(aptr[t] + kn) : z4;
#pragma unroll
      for (int u = 0; u < 2; u++)
        pb[u] = *reinterpret_cast<const int4*>(bptr[u] + kn);
    }
    __syncthreads();
    short8 af[4], bfv[4];
#pragma unroll
    for (int i = 0; i < 4; i++)
      af[i] = *reinterpret_cast<const short8*>(
          &Alds[(wm + i * 16 + lr) * LDT + quad * 8]);
#pragma unroll
    for (int j = 0; j < 4; j++)
      bfv[j] = *reinterpret_cast<const short8*>(
          &Blds[(wn + j * 16 + lr) * LDT + quad * 8]);
#pragma unroll
    for (int i = 0; i < 4; i++)
#pragma unroll
      for (int j = 0; j < 4; j++)
        acc[i][j] = __builtin_amdgcn_mfma_f32_16x16x32_bf16(af[i], bfv[j],
                                                            acc[i][j], 0, 0, 0);
    __syncthreads();
  }
  // epilogue: C/D layout col=lane&15, row=quad*4+reg
#pragma unroll
  for (int i = 0; i < 4; i++) {
#pragma unroll
    for (int j = 0; j < 4; j++) {
      int n = n0 + wn + j * 16 + lr;
      float bv = bias ? bias[n] : 0.f;
#pragma unroll
      for (int r = 0; r < 4; r++) {
        int m = m0 + wm + i * 16 + quad * 4 + r;
        if (m < M) Y[(size_t)m * N + n] = acc[i][j][r] + bv;
      }
    }
  }
}

// ---------------------------------------------------------------------------
// fp32 fallback GEMM (MLP head, N=153)
// ---------------------------------------------------------------------------
__global__ __launch_bounds__(256) void gemm_bias(
    const float* __restrict__ A, const float* __restrict__ W,
    const float* __restrict__ bias, float* __restrict__ Y,
    const int* __restrict__ idx, int M, int K, int N) {
  __shared__ float As[16][65];
  __shared__ float Bs[16][64];
  int tid = threadIdx.x;
  int tx = tid & 15, ty = tid >> 4;
  int m0 = blockIdx.x * 64, n0 = blockIdx.y * 64;
  float acc[4][4] = {};
  for (int k0 = 0; k0 < K; k0 += 16) {
    for (int l = tid; l < 64 * 16; l += 256) {
      int r = l >> 4, kk = l & 15;
      int row = m0 + r;
      float v = 0.f;
      if (row < M) {
        int ar = idx ? idx[row] : row;
        v = A[(size_t)ar * K + k0 + kk];
      }
      As[kk][r] = v;
    }
    for (int l = tid; l < 16 * 64; l += 256) {
      int kk = l >> 6, n = l & 63;
      int col = n0 + n;
      Bs[kk][n] = (col < N) ? W[(size_t)(k0 + kk) * N + col] : 0.f;
    }
    __syncthreads();
#pragma unroll
    for (int kk = 0; kk < 16; kk++) {
      float a[4], b[4];
#pragma unroll
      for (int i = 0; i < 4; i++) a[i] = As[kk][ty + 16 * i];
#pragma unroll
      for (int j = 0; j < 4; j++) b[j] = Bs[kk][tx + 16 * j];
#pragma unroll
      for (int i = 0; i < 4; i++)
#pragma unroll
        for (int j = 0; j < 4; j++) acc[i][j] += a[i] * b[j];
    }
    __syncthreads();
  }
#pragma unroll
  for (int i = 0; i < 4; i++) {
    int m = m0 + ty + 16 * i;
    if (m >= M) continue;
#pragma unroll
    for (int j = 0; j < 4; j++) {
      int n = n0 + tx + 16 * j;
      if (n < N) Y[(size_t)m * N + n] = acc[i][j] + (bias ? bias[n] : 0.f);
    }
  }
}

// ---------------------------------------------------------------------------
__global__ __launch_bounds__(256) void att_scores(
    const float* __restrict__ x, const float* __restrict__ attS,
    const float* __restrict__ attD, float* __restrict__ a_s,
    float* __restrict__ a_d, int Ns, int Nd) {
  int w = blockIdx.x * 4 + (threadIdx.x >> 6);
  int lane = threadIdx.x & 63;
  int i = w >> 2, h = w & 3;
  if (i >= Ns) return;
  const float* xr = x + (size_t)i * 512 + h * 128;
  float v1 = xr[lane], v2 = xr[lane + 64];
  float s = waveSum(v1 * attS[h * 128 + lane] + v2 * attS[h * 128 + lane + 64]);
  if (lane == 0) a_s[i * 4 + h] = s;
  if (i < Nd) {
    float d = waveSum(v1 * attD[h * 128 + lane] + v2 * attD[h * 128 + lane + 64]);
    if (lane == 0) a_d[i * 4 + h] = d;
  }
}

__global__ void build_starts(const int* __restrict__ dst, int E, int n_dst,
                             int* __restrict__ starts) {
  int k = blockIdx.x * 256 + threadIdx.x;
  if (k > E) return;
  if (k == 0) {
    int d0 = dst[0];
    for (int j = 0; j <= d0; j++) starts[j] = 0;
  } else if (k < E) {
    int d = dst[k], dp = dst[k - 1];
    for (int j = dp + 1; j <= d; j++) starts[j] = k;
  } else {
    int dl = dst[E - 1];
    for (int j = dl + 1; j <= n_dst; j++) starts[j] = E;
  }
}

__global__ void edge_logits(const int* __restrict__ src, const int* __restrict__ dst,
                            const float* __restrict__ a_s, const float* __restrict__ a_d,
                            float* __restrict__ logits, int E) {
  int k = blockIdx.x * 256 + threadIdx.x;
  if (k >= E) return;
  int s = src[k], d = dst[k];
#pragma unroll
  for (int h = 0; h < 4; h++) {
    float v = a_s[s * 4 + h] + a_d[d * 4 + h];
    v = (v >= 0.f) ? v : 0.2f * v;
    logits[k * 4 + h] = v;
  }
}

__global__ void node_ms(const float* __restrict__ logits, const int* __restrict__ starts,
                        float* __restrict__ ms, int n_dst) {
  int t = blockIdx.x * 256 + threadIdx.x;
  int j = t >> 2, h = t & 3;
  if (j >= n_dst) return;
  int r0 = starts[j], r1 = starts[j + 1];
  float m = -1e30f;
  for (int k = r0; k < r1; k++) m = fmaxf(m, logits[k * 4 + h]);
  float s = 0.f;
  for (int k = r0; k < r1; k++) s += __expf(logits[k * 4 + h] - m);
  ms[j * 8 + h] = m;
  ms[j * 8 + 4 + h] = s;
}

__global__ void edge_coef(float* __restrict__ logits, const int* __restrict__ dst,
                          const float* __restrict__ ms, int E) {
  int k = blockIdx.x * 256 + threadIdx.x;
  if (k >= E) return;
  int d = dst[k];
#pragma unroll
  for (int h = 0; h < 4; h++) {
    float m = ms[d * 8 + h], s = ms[d * 8 + 4 + h];
    logits[k * 4 + h] = __expf(logits[k * 4 + h] - m) / fmaxf(s, 1e-16f);
  }
}

__global__ __launch_bounds__(128) void gat_aggregate(
    const float* __restrict__ x, const float* __restrict__ coef,
    const int* __restrict__ src, const int* __restrict__ starts,
    const float* __restrict__ bg, float* __restrict__ o, int n_dst) {
  int j = blockIdx.x;
  int c = threadIdx.x;
  int r0 = starts[j], r1 = starts[j + 1];
  float a0 = 0.f, a1 = 0.f, a2 = 0.f, a3 = 0.f;
  for (int k = r0; k < r1; k++) {
    int s = src[k];
    const float* xr = x + (size_t)s * 512;
    float c0 = coef[k * 4 + 0], c1 = coef[k * 4 + 1];
    float c2 = coef[k * 4 + 2], c3 = coef[k * 4 + 3];
    a0 += c0 * xr[c];
    a1 += c1 * xr[128 + c];
    a2 += c2 * xr[256 + c];
    a3 += c3 * xr[384 + c];
  }
  o[(size_t)j * 128 + c] = 0.25f * (a0 + a1 + a2 + a3) + bg[c];
}

// ---------------------------------------------------------------------------
// BatchNorm stats: 960 partial blocks; finalize = 128 blocks (one channel
// each), wave-reduce over partials. bn_apply fuses activation.
// ---------------------------------------------------------------------------
__global__ __launch_bounds__(128) void bn_partial(const float* __restrict__ x,
                                                  float* __restrict__ partial, int N) {
  int c = threadIdx.x;
  float s = 0.f, ss = 0.f;
  for (int r = blockIdx.x; r < N; r += gridDim.x) {
    float v = x[(size_t)r * 128 + c];
    s += v;
    ss += v * v;
  }
  partial[blockIdx.x * 256 + c] = s;
  partial[blockIdx.x * 256 + 128 + c] = ss;
}

__global__ __launch_bounds__(64) void bn_finalize(const float* __restrict__ partial,
                                                  int G, int N, float* __restrict__ stats) {
  int c = blockIdx.x;      // channel 0..127
  int lane = threadIdx.x;  // 0..63
  float s = 0.f, ss = 0.f;
  for (int b = lane; b < G; b += 64) {
    s += partial[b * 256 + c];
    ss += partial[b * 256 + 128 + c];
  }
  s = waveSum(s);
  ss = waveSum(ss);
  if (lane == 0) {
    float mu = s / (float)N;
    float var = ss / (float)N - mu * mu;
    stats[c] = mu;
    stats[128 + c] = rsqrtf(var + EPSV);
  }
}

__global__ __launch_bounds__(128) void bn_apply(
    const float* __restrict__ x, const float* __restrict__ stats,
    const float* __restrict__ g, const float* __restrict__ b,
    float* __restrict__ y, int M, int ostride, int act) {
  int r = blockIdx.x;
  int c = threadIdx.x;
  if (r >= M) return;
  float v = x[(size_t)r * 128 + c];
  v = (v - stats[c]) * stats[128 + c] * g[c] + b[c];
  if (act == 1) v = (v > 0.f) ? v : (__expf(v) - 1.f);
  if (act == 2) v = fmaxf(v, 0.f);
  y[(size_t)r * ostride + c] = v;
}

__global__ __launch_bounds__(128) void pool_attn(
    const float* __restrict__ temp, const float* __restrict__ wp,
    const float* __restrict__ bp, float* __restrict__ sk, int batch) {
  int b = blockIdx.x, c = threadIdx.x;
  int lane = c & 63, wid = c >> 6;
  __shared__ float red[12];
  const float* tr = temp + (size_t)b * 768;
  float wpc = wp[c];
  float t[6];
#pragma unroll
  for (int p = 0; p < 6; p++) t[p] = tr[p * 128 + c];
#pragma unroll
  for (int p = 0; p < 6; p++) {
    float v = waveSum(t[p] * wpc);
    if (lane == 0) red[wid * 6 + p] = v;
  }
  __syncthreads();
  float z[6], m = -1e30f;
#pragma unroll
  for (int p = 0; p < 6; p++) {
    z[p] = red[p] + red[6 + p] + bp[0];
    m = fmaxf(m, z[p]);
  }
  float es = 0.f;
#pragma unroll
  for (int p = 0; p < 6; p++) {
    z[p] = __expf(z[p] - m);
    es += z[p];
  }
  float inv = 1.f / es;
  float o = 0.f;
#pragma unroll
  for (int p = 0; p < 6; p++) o += z[p] * inv * t[p];
  sk[(size_t)b * 128 + c] = o;
}

// ---------------------------------------------------------------------------
extern "C" void kernel_launch(void* const* d_in, const int* in_sizes, int n_in,
                              void* d_out, int out_size, void* d_ws, size_t ws_size,
                              hipStream_t stream) {
  const float* feature = (const float*)d_in[0];
  const int* nodes_idx[2] = {(const int*)d_in[1], (const int*)d_in[4]};
  const int* edge_src[2] = {(const int*)d_in[2], (const int*)d_in[5]};
  const int* edge_dst[2] = {(const int*)d_in[3], (const int*)d_in[6]};
  const float *Wsk[2], *bsk[2], *bng[2], *bnb[2], *Wg[2], *attS[2], *attD[2],
      *bg[2], *wp[2], *bp[2], *pg[2], *pb[2];
  for (int l = 0; l < 2; l++) {
    int base = 7 + l * 12;
    Wsk[l] = (const float*)d_in[base + 0];
    bsk[l] = (const float*)d_in[base + 1];
    bng[l] = (const float*)d_in[base + 2];
    bnb[l] = (const float*)d_in[base + 3];
    Wg[l] = (const float*)d_in[base + 4];
    attS[l] = (const float*)d_in[base + 5];
    attD[l] = (const float*)d_in[base + 6];
    bg[l] = (const float*)d_in[base + 7];
    wp[l] = (const float*)d_in[base + 8];
    bp[l] = (const float*)d_in[base + 9];
    pg[l] = (const float*)d_in[base + 10];
    pb[l] = (const float*)d_in[base + 11];
  }
  const float* Wm1 = (const float*)d_in[31];
  const float* bm1 = (const float*)d_in[32];
  const float* mg = (const float*)d_in[33];
  const float* mb = (const float*)d_in[34];
  const float* Wm2 = (const float*)d_in[35];
  const float* bm2 = (const float*)d_in[36];

  // ---- workspace layout (float units) ----
  float* ws = (float*)d_ws;
  float* bufG = ws;   ws += 20480000;  // 40000*512 (also skip out 100000*128)
  float* bufO = ws;   ws += 3840000;   // 30000*128
  float* temp = ws;   ws += 19200000;  // 25000*6*128
  float* f0   = ws;   ws += 3200000;   // 25000*128
  float* f1   = ws;   ws += 1024000;   // 8000*128
  float* bufH = ws;   ws += 1024000;   // 8000*128
  float* a_s  = ws;   ws += 160000;    // 40000*4
  float* a_d  = ws;   ws += 120000;    // 30000*4
  float* logi = ws;   ws += 800000;    // 200000*4
  float* ms   = ws;   ws += 240000;    // 30000*8
  float* part = ws;   ws += NSTATB * 256;
  float* stats = ws;  ws += 256;
  int* starts = (int*)ws; ws += 30016; // 30001 ints
  short* wt_sk0 = (short*)ws; ws += 32768;   // 128*512 shorts
  short* wt_g0  = (short*)ws; ws += 655360;  // 5*512*512 shorts
  short* wt_sk1 = (short*)ws; ws += 8192;    // 128*128 shorts
  short* wt_g1  = (short*)ws; ws += 163840;  // 5*512*128 shorts

  auto cdiv = [](int a, int b) { return (a + b - 1) / b; };

  wT_bf16<<<dim3(16, 4), 256, 0, stream>>>(Wsk[0], wt_sk0, 512, 128);
  for (int e2 = 0; e2 < 5; e2++)
    wT_bf16<<<dim3(16, 16), 256, 0, stream>>>(Wg[0] + (size_t)e2 * 512 * 512,
                                              wt_g0 + (size_t)e2 * 512 * 512, 512, 512);
  wT_bf16<<<dim3(4, 4), 256, 0, stream>>>(Wsk[1], wt_sk1, 128, 128);
  for (int e2 = 0; e2 < 5; e2++)
    wT_bf16<<<dim3(4, 16), 256, 0, stream>>>(Wg[1] + (size_t)e2 * 128 * 512,
                                             wt_g1 + (size_t)e2 * 512 * 128, 128, 512);

  auto run_layer = [&](const float* X, int Nf, int din, int li, float* fout,
                       const short* wt_sk, const short* wt_g) {
    const int Nsrc = (li == 0) ? 40000 : 20000;
    const int n_dst = (li == 0) ? 30000 : 10000;
    const int batch = (li == 0) ? 25000 : 8000;
    const int E = (li == 0) ? 200000 : 80000;

    gemm_mfma<<<dim3(1, cdiv(Nf, 128)), 256, 0, stream>>>(
        X, wt_sk, bsk[li], bufG, nullptr, Nf, din, 128);
    bn_partial<<<NSTATB, 128, 0, stream>>>(bufG, part, Nf);
    bn_finalize<<<128, 64, 0, stream>>>(part, NSTATB, Nf, stats);
    bn_apply<<<batch, 128, 0, stream>>>(bufG, stats, bng[li], bnb[li], temp,
                                        batch, 768, 1);

    for (int e2 = 0; e2 < 5; e2++) {
      const int* idx = nodes_idx[li] + (size_t)e2 * Nsrc;
      const int* src = edge_src[li] + (size_t)e2 * E;
      const int* dst = edge_dst[li] + (size_t)e2 * E;
      gemm_mfma<<<dim3(4, cdiv(Nsrc, 128)), 256, 0, stream>>>(
          X, wt_g + (size_t)e2 * din * 512, nullptr, bufG, idx, Nsrc, din, 512);
      att_scores<<<Nsrc, 256, 0, stream>>>(bufG, attS[li] + e2 * 512,
                                           attD[li] + e2 * 512, a_s, a_d, Nsrc, n_dst);
      build_starts<<<cdiv(E + 1, 256), 256, 0, stream>>>(dst, E, n_dst, starts);
      edge_logits<<<cdiv(E, 256), 256, 0, stream>>>(src, dst, a_s, a_d, logi, E);
      node_ms<<<cdiv(n_dst * 4, 256), 256, 0, stream>>>(logi, starts, ms, n_dst);
      edge_coef<<<cdiv(E, 256), 256, 0, stream>>>(logi, dst, ms, E);
      gat_aggregate<<<n_dst, 128, 0, stream>>>(bufG, logi, src, starts,
                                               bg[li] + e2 * 128, bufO, n_dst);
      bn_partial<<<NSTATB, 128, 0, stream>>>(bufO, part, n_dst);
      bn_finalize<<<128, 64, 0, stream>>>(part, NSTATB, n_dst, stats);
      bn_apply<<<batch, 128, 0, stream>>>(bufO, stats, bng[li] + (e2 + 1) * 128,
                                          bnb[li] + (e2 + 1) * 128,
                                          temp + (e2 + 1) * 128, batch, 768, 1);
    }

    pool_attn<<<batch, 128, 0, stream>>>(temp, wp[li], bp[li], bufO, batch);
    bn_partial<<<NSTATB, 128, 0, stream>>>(bufO, part, batch);
    bn_finalize<<<128, 64, 0, stream>>>(part, NSTATB, batch, stats);
    bn_apply<<<batch, 128, 0, stream>>>(bufO, stats, pg[li], pb[li], fout, batch,
                                        128, 0);
  };

  run_layer(feature, 100000, 512, 0, f0, wt_sk0, wt_g0);
  run_layer(f0, 25000, 128, 1, f1, wt_sk1, wt_g1);

  gemm_bias<<<dim3(cdiv(8000, 64), 2), 256, 0, stream>>>(f1, Wm1, bm1, bufG,
                                                         nullptr, 8000, 128, 128);
  bn_partial<<<NSTATB, 128, 0, stream>>>(bufG, part, 8000);
  bn_finalize<<<128, 64, 0, stream>>>(part, NSTATB, 8000, stats);
  bn_apply<<<8000, 128, 0, stream>>>(bufG, stats, mg, mb, bufH, 8000, 128, 2);
  gemm_bias<<<dim3(cdiv(8000, 64), 3), 256, 0, stream>>>(
      bufH, Wm2, bm2, (float*)d_out, nullptr, 8000, 128, 153);
}

// Round 8
// 2093.908 us; speedup vs baseline: 1.1945x; 1.1709x over previous
//
#include <hip/hip_runtime.h>
#include <math.h>

#define EPSV 1e-5f
#define NSTATB 960

typedef __attribute__((ext_vector_type(8))) short short8;
typedef __attribute__((ext_vector_type(4))) float floatx4;

__device__ __forceinline__ float waveSum(float v) {
#pragma unroll
  for (int off = 32; off > 0; off >>= 1) v += __shfl_xor(v, off, 64);
  return v;
}

__device__ __forceinline__ unsigned bfr(float f) {
  union { float f; unsigned u; } v;
  v.f = f;
  return (v.u + 0x7FFFu + ((v.u >> 16) & 1u)) >> 16;  // round-nearest-even
}

// ---------------------------------------------------------------------------
// Transpose + convert: Wt[n*K + k] = bf16(W[k*N + n])
// ---------------------------------------------------------------------------
__global__ __launch_bounds__(256) void wT_bf16(const float* __restrict__ W,
                                               short* __restrict__ Wt, int K, int N) {
  __shared__ short t[32][33];
  int k0 = blockIdx.x * 32, n0 = blockIdx.y * 32;
  int x = threadIdx.x & 31, y = threadIdx.x >> 5;  // 32 x 8
#pragma unroll
  for (int dy = 0; dy < 32; dy += 8) {
    int k = k0 + y + dy, n = n0 + x;
    t[y + dy][x] = (k < K && n < N) ? (short)bfr(W[(size_t)k * N + n]) : (short)0;
  }
  __syncthreads();
#pragma unroll
  for (int dy = 0; dy < 32; dy += 8) {
    int n = n0 + y + dy, k = k0 + x;
    if (n < N && k < K) Wt[(size_t)n * K + k] = t[x][y + dy];
  }
}

// ---------------------------------------------------------------------------
// MFMA GEMM: Y[m,n] = sum_k bf16(A[row(m),k]) * Wt_bf16[n,k] (+ bias[n])
// 128x128 tile, BK=32, 512 threads = 8 waves (2x4: each wave 64x32 of C).
// Each thread stages ONE LDS row chunk (1 row index, 8 floats A, 8 shorts B)
// -> prefetch state ~14 regs; acc = 4x2 frags = 32 regs. No spill (R6/R7
// lesson: 256-thr version had ~110 live regs and spilled ~100MB/dispatch).
// Requires: K % 32 == 0, N % 128 == 0, A rows 16B-aligned (K%4==0).
// ---------------------------------------------------------------------------
__global__ __launch_bounds__(512) void gemm_mfma(
    const float* __restrict__ A, const short* __restrict__ Wt,
    const float* __restrict__ bias, float* __restrict__ Y,
    const int* __restrict__ idx, int M, int K, int N) {
  constexpr int LDT = 40;  // padded LDS row stride (shorts): 2-way banks max
  __shared__ short Alds[128 * LDT];
  __shared__ short Blds[128 * LDT];
  int tid = threadIdx.x;
  int m0 = blockIdx.y * 128, n0 = blockIdx.x * 128;

  // staging: thread t covers LDS row t>>2, elem chunk (t&3)*8
  int srow = tid >> 2, sc = (tid & 3) * 8;
  int grow = m0 + srow;
  int ar = (grow < M) ? (idx ? idx[grow] : grow) : -1;
  const float* abase = (ar >= 0) ? A + (size_t)ar * K + sc : nullptr;
  const short* bbase = Wt + (size_t)(n0 + srow) * K + sc;

  int wave = tid >> 6, lane = tid & 63;
  int wm = (wave & 1) * 64, wn = (wave >> 1) * 32;
  int lr = lane & 15, quad = lane >> 4;
  floatx4 acc[4][2];
#pragma unroll
  for (int i = 0; i < 4; i++)
#pragma unroll
    for (int j = 0; j < 2; j++) acc[i][j] = (floatx4)0.f;

  float4 pa0, pa1;
  int4 pb;
  float4 z4;
  z4.x = z4.y = z4.z = z4.w = 0.f;

  // prologue: tile k=0
  if (abase) {
    pa0 = *reinterpret_cast<const float4*>(abase);
    pa1 = *reinterpret_cast<const float4*>(abase + 4);
  } else {
    pa0 = z4;
    pa1 = z4;
  }
  pb = *reinterpret_cast<const int4*>(bbase);

  for (int k0 = 0; k0 < K; k0 += 32) {
    // write staged registers to LDS (8-B stores: LDT=40 is 8-B aligned)
    uint2 w0, w1;
    w0.x = bfr(pa0.x) | (bfr(pa0.y) << 16);
    w0.y = bfr(pa0.z) | (bfr(pa0.w) << 16);
    w1.x = bfr(pa1.x) | (bfr(pa1.y) << 16);
    w1.y = bfr(pa1.z) | (bfr(pa1.w) << 16);
    *reinterpret_cast<uint2*>(&Alds[srow * LDT + sc]) = w0;
    *reinterpret_cast<uint2*>(&Alds[srow * LDT + sc + 4]) = w1;
    *reinterpret_cast<uint2*>(&Blds[srow * LDT + sc]) =
        make_uint2((unsigned)pb.x, (unsigned)pb.y);
    *reinterpret_cast<uint2*>(&Blds[srow * LDT + sc + 4]) =
        make_uint2((unsigned)pb.z, (unsigned)pb.w);
    // prefetch next tile BEFORE the barrier -> latency overlaps MFMA phase
    if (k0 + 32 < K) {
      int kn = k0 + 32;
      if (abase) {
        pa0 = *reinterpret_cast<const float4*>(abase + kn);
        pa1 = *reinterpret_cast<const float4*>(abase + kn + 4);
      }
      pb = *reinterpret_cast<const int4*>(bbase + kn);
    }
    __syncthreads();
    short8 af[4], bfv[2];
#pragma unroll
    for (int i = 0; i < 4; i++)
      af[i] = *reinterpret_cast<const short8*>(
          &Alds[(wm + i * 16 + lr) * LDT + quad * 8]);
#pragma unroll
    for (int j = 0; j < 2; j++)
      bfv[j] = *reinterpret_cast<const short8*>(
          &Blds[(wn + j * 16 + lr) * LDT + quad * 8]);
#pragma unroll
    for (int i = 0; i < 4; i++)
#pragma unroll
      for (int j = 0; j < 2; j++)
        acc[i][j] = __builtin_amdgcn_mfma_f32_16x16x32_bf16(af[i], bfv[j],
                                                            acc[i][j], 0, 0, 0);
    __syncthreads();
  }
  // epilogue: C/D layout col=lane&15, row=quad*4+reg
#pragma unroll
  for (int i = 0; i < 4; i++) {
#pragma unroll
    for (int j = 0; j < 2; j++) {
      int n = n0 + wn + j * 16 + lr;
      float bv = bias ? bias[n] : 0.f;
#pragma unroll
      for (int r = 0; r < 4; r++) {
        int m = m0 + wm + i * 16 + quad * 4 + r;
        if (m < M) Y[(size_t)m * N + n] = acc[i][j][r] + bv;
      }
    }
  }
}

// ---------------------------------------------------------------------------
// fp32 fallback GEMM (MLP head, N=153)
// ---------------------------------------------------------------------------
__global__ __launch_bounds__(256) void gemm_bias(
    const float* __restrict__ A, const float* __restrict__ W,
    const float* __restrict__ bias, float* __restrict__ Y,
    const int* __restrict__ idx, int M, int K, int N) {
  __shared__ float As[16][65];
  __shared__ float Bs[16][64];
  int tid = threadIdx.x;
  int tx = tid & 15, ty = tid >> 4;
  int m0 = blockIdx.x * 64, n0 = blockIdx.y * 64;
  float acc[4][4] = {};
  for (int k0 = 0; k0 < K; k0 += 16) {
    for (int l = tid; l < 64 * 16; l += 256) {
      int r = l >> 4, kk = l & 15;
      int row = m0 + r;
      float v = 0.f;
      if (row < M) {
        int ar = idx ? idx[row] : row;
        v = A[(size_t)ar * K + k0 + kk];
      }
      As[kk][r] = v;
    }
    for (int l = tid; l < 16 * 64; l += 256) {
      int kk = l >> 6, n = l & 63;
      int col = n0 + n;
      Bs[kk][n] = (col < N) ? W[(size_t)(k0 + kk) * N + col] : 0.f;
    }
    __syncthreads();
#pragma unroll
    for (int kk = 0; kk < 16; kk++) {
      float a[4], b[4];
#pragma unroll
      for (int i = 0; i < 4; i++) a[i] = As[kk][ty + 16 * i];
#pragma unroll
      for (int j = 0; j < 4; j++) b[j] = Bs[kk][tx + 16 * j];
#pragma unroll
      for (int i = 0; i < 4; i++)
#pragma unroll
        for (int j = 0; j < 4; j++) acc[i][j] += a[i] * b[j];
    }
    __syncthreads();
  }
#pragma unroll
  for (int i = 0; i < 4; i++) {
    int m = m0 + ty + 16 * i;
    if (m >= M) continue;
#pragma unroll
    for (int j = 0; j < 4; j++) {
      int n = n0 + tx + 16 * j;
      if (n < N) Y[(size_t)m * N + n] = acc[i][j] + (bias ? bias[n] : 0.f);
    }
  }
}

// ---------------------------------------------------------------------------
__global__ __launch_bounds__(256) void att_scores(
    const float* __restrict__ x, const float* __restrict__ attS,
    const float* __restrict__ attD, float* __restrict__ a_s,
    float* __restrict__ a_d, int Ns, int Nd) {
  int w = blockIdx.x * 4 + (threadIdx.x >> 6);
  int lane = threadIdx.x & 63;
  int i = w >> 2, h = w & 3;
  if (i >= Ns) return;
  const float* xr = x + (size_t)i * 512 + h * 128;
  float v1 = xr[lane], v2 = xr[lane + 64];
  float s = waveSum(v1 * attS[h * 128 + lane] + v2 * attS[h * 128 + lane + 64]);
  if (lane == 0) a_s[i * 4 + h] = s;
  if (i < Nd) {
    float d = waveSum(v1 * attD[h * 128 + lane] + v2 * attD[h * 128 + lane + 64]);
    if (lane == 0) a_d[i * 4 + h] = d;
  }
}

__global__ void build_starts(const int* __restrict__ dst, int E, int n_dst,
                             int* __restrict__ starts) {
  int k = blockIdx.x * 256 + threadIdx.x;
  if (k > E) return;
  if (k == 0) {
    int d0 = dst[0];
    for (int j = 0; j <= d0; j++) starts[j] = 0;
  } else if (k < E) {
    int d = dst[k], dp = dst[k - 1];
    for (int j = dp + 1; j <= d; j++) starts[j] = k;
  } else {
    int dl = dst[E - 1];
    for (int j = dl + 1; j <= n_dst; j++) starts[j] = E;
  }
}

__global__ void edge_logits(const int* __restrict__ src, const int* __restrict__ dst,
                            const float* __restrict__ a_s, const float* __restrict__ a_d,
                            float* __restrict__ logits, int E) {
  int k = blockIdx.x * 256 + threadIdx.x;
  if (k >= E) return;
  int s = src[k], d = dst[k];
#pragma unroll
  for (int h = 0; h < 4; h++) {
    float v = a_s[s * 4 + h] + a_d[d * 4 + h];
    v = (v >= 0.f) ? v : 0.2f * v;
    logits[k * 4 + h] = v;
  }
}

__global__ void node_ms(const float* __restrict__ logits, const int* __restrict__ starts,
                        float* __restrict__ ms, int n_dst) {
  int t = blockIdx.x * 256 + threadIdx.x;
  int j = t >> 2, h = t & 3;
  if (j >= n_dst) return;
  int r0 = starts[j], r1 = starts[j + 1];
  float m = -1e30f;
  for (int k = r0; k < r1; k++) m = fmaxf(m, logits[k * 4 + h]);
  float s = 0.f;
  for (int k = r0; k < r1; k++) s += __expf(logits[k * 4 + h] - m);
  ms[j * 8 + h] = m;
  ms[j * 8 + 4 + h] = s;
}

__global__ void edge_coef(float* __restrict__ logits, const int* __restrict__ dst,
                          const float* __restrict__ ms, int E) {
  int k = blockIdx.x * 256 + threadIdx.x;
  if (k >= E) return;
  int d = dst[k];
#pragma unroll
  for (int h = 0; h < 4; h++) {
    float m = ms[d * 8 + h], s = ms[d * 8 + 4 + h];
    logits[k * 4 + h] = __expf(logits[k * 4 + h] - m) / fmaxf(s, 1e-16f);
  }
}

__global__ __launch_bounds__(128) void gat_aggregate(
    const float* __restrict__ x, const float* __restrict__ coef,
    const int* __restrict__ src, const int* __restrict__ starts,
    const float* __restrict__ bg, float* __restrict__ o, int n_dst) {
  int j = blockIdx.x;
  int c = threadIdx.x;
  int r0 = starts[j], r1 = starts[j + 1];
  float a0 = 0.f, a1 = 0.f, a2 = 0.f, a3 = 0.f;
  for (int k = r0; k < r1; k++) {
    int s = src[k];
    const float* xr = x + (size_t)s * 512;
    float c0 = coef[k * 4 + 0], c1 = coef[k * 4 + 1];
    float c2 = coef[k * 4 + 2], c3 = coef[k * 4 + 3];
    a0 += c0 * xr[c];
    a1 += c1 * xr[128 + c];
    a2 += c2 * xr[256 + c];
    a3 += c3 * xr[384 + c];
  }
  o[(size_t)j * 128 + c] = 0.25f * (a0 + a1 + a2 + a3) + bg[c];
}

// ---------------------------------------------------------------------------
// BatchNorm stats: 960 partial blocks; finalize = 128 blocks (one channel
// each), wave-reduce over partials. bn_apply fuses activation.
// ---------------------------------------------------------------------------
__global__ __launch_bounds__(128) void bn_partial(const float* __restrict__ x,
                                                  float* __restrict__ partial, int N) {
  int c = threadIdx.x;
  float s = 0.f, ss = 0.f;
  for (int r = blockIdx.x; r < N; r += gridDim.x) {
    float v = x[(size_t)r * 128 + c];
    s += v;
    ss += v * v;
  }
  partial[blockIdx.x * 256 + c] = s;
  partial[blockIdx.x * 256 + 128 + c] = ss;
}

__global__ __launch_bounds__(64) void bn_finalize(const float* __restrict__ partial,
                                                  int G, int N, float* __restrict__ stats) {
  int c = blockIdx.x;      // channel 0..127
  int lane = threadIdx.x;  // 0..63
  float s = 0.f, ss = 0.f;
  for (int b = lane; b < G; b += 64) {
    s += partial[b * 256 + c];
    ss += partial[b * 256 + 128 + c];
  }
  s = waveSum(s);
  ss = waveSum(ss);
  if (lane == 0) {
    float mu = s / (float)N;
    float var = ss / (float)N - mu * mu;
    stats[c] = mu;
    stats[128 + c] = rsqrtf(var + EPSV);
  }
}

__global__ __launch_bounds__(128) void bn_apply(
    const float* __restrict__ x, const float* __restrict__ stats,
    const float* __restrict__ g, const float* __restrict__ b,
    float* __restrict__ y, int M, int ostride, int act) {
  int r = blockIdx.x;
  int c = threadIdx.x;
  if (r >= M) return;
  float v = x[(size_t)r * 128 + c];
  v = (v - stats[c]) * stats[128 + c] * g[c] + b[c];
  if (act == 1) v = (v > 0.f) ? v : (__expf(v) - 1.f);
  if (act == 2) v = fmaxf(v, 0.f);
  y[(size_t)r * ostride + c] = v;
}

__global__ __launch_bounds__(128) void pool_attn(
    const float* __restrict__ temp, const float* __restrict__ wp,
    const float* __restrict__ bp, float* __restrict__ sk, int batch) {
  int b = blockIdx.x, c = threadIdx.x;
  int lane = c & 63, wid = c >> 6;
  __shared__ float red[12];
  const float* tr = temp + (size_t)b * 768;
  float wpc = wp[c];
  float t[6];
#pragma unroll
  for (int p = 0; p < 6; p++) t[p] = tr[p * 128 + c];
#pragma unroll
  for (int p = 0; p < 6; p++) {
    float v = waveSum(t[p] * wpc);
    if (lane == 0) red[wid * 6 + p] = v;
  }
  __syncthreads();
  float z[6], m = -1e30f;
#pragma unroll
  for (int p = 0; p < 6; p++) {
    z[p] = red[p] + red[6 + p] + bp[0];
    m = fmaxf(m, z[p]);
  }
  float es = 0.f;
#pragma unroll
  for (int p = 0; p < 6; p++) {
    z[p] = __expf(z[p] - m);
    es += z[p];
  }
  float inv = 1.f / es;
  float o = 0.f;
#pragma unroll
  for (int p = 0; p < 6; p++) o += z[p] * inv * t[p];
  sk[(size_t)b * 128 + c] = o;
}

// ---------------------------------------------------------------------------
extern "C" void kernel_launch(void* const* d_in, const int* in_sizes, int n_in,
                              void* d_out, int out_size, void* d_ws, size_t ws_size,
                              hipStream_t stream) {
  const float* feature = (const float*)d_in[0];
  const int* nodes_idx[2] = {(const int*)d_in[1], (const int*)d_in[4]};
  const int* edge_src[2] = {(const int*)d_in[2], (const int*)d_in[5]};
  const int* edge_dst[2] = {(const int*)d_in[3], (const int*)d_in[6]};
  const float *Wsk[2], *bsk[2], *bng[2], *bnb[2], *Wg[2], *attS[2], *attD[2],
      *bg[2], *wp[2], *bp[2], *pg[2], *pb[2];
  for (int l = 0; l < 2; l++) {
    int base = 7 + l * 12;
    Wsk[l] = (const float*)d_in[base + 0];
    bsk[l] = (const float*)d_in[base + 1];
    bng[l] = (const float*)d_in[base + 2];
    bnb[l] = (const float*)d_in[base + 3];
    Wg[l] = (const float*)d_in[base + 4];
    attS[l] = (const float*)d_in[base + 5];
    attD[l] = (const float*)d_in[base + 6];
    bg[l] = (const float*)d_in[base + 7];
    wp[l] = (const float*)d_in[base + 8];
    bp[l] = (const float*)d_in[base + 9];
    pg[l] = (const float*)d_in[base + 10];
    pb[l] = (const float*)d_in[base + 11];
  }
  const float* Wm1 = (const float*)d_in[31];
  const float* bm1 = (const float*)d_in[32];
  const float* mg = (const float*)d_in[33];
  const float* mb = (const float*)d_in[34];
  const float* Wm2 = (const float*)d_in[35];
  const float* bm2 = (const float*)d_in[36];

  // ---- workspace layout (float units) ----
  float* ws = (float*)d_ws;
  float* bufG = ws;   ws += 20480000;  // 40000*512 (also skip out 100000*128)
  float* bufO = ws;   ws += 3840000;   // 30000*128
  float* temp = ws;   ws += 19200000;  // 25000*6*128
  float* f0   = ws;   ws += 3200000;   // 25000*128
  float* f1   = ws;   ws += 1024000;   // 8000*128
  float* bufH = ws;   ws += 1024000;   // 8000*128
  float* a_s  = ws;   ws += 160000;    // 40000*4
  float* a_d  = ws;   ws += 120000;    // 30000*4
  float* logi = ws;   ws += 800000;    // 200000*4
  float* ms   = ws;   ws += 240000;    // 30000*8
  float* part = ws;   ws += NSTATB * 256;
  float* stats = ws;  ws += 256;
  int* starts = (int*)ws; ws += 30016; // 30001 ints
  short* wt_sk0 = (short*)ws; ws += 32768;   // 128*512 shorts
  short* wt_g0  = (short*)ws; ws += 655360;  // 5*512*512 shorts
  short* wt_sk1 = (short*)ws; ws += 8192;    // 128*128 shorts
  short* wt_g1  = (short*)ws; ws += 163840;  // 5*512*128 shorts

  auto cdiv = [](int a, int b) { return (a + b - 1) / b; };

  wT_bf16<<<dim3(16, 4), 256, 0, stream>>>(Wsk[0], wt_sk0, 512, 128);
  for (int e2 = 0; e2 < 5; e2++)
    wT_bf16<<<dim3(16, 16), 256, 0, stream>>>(Wg[0] + (size_t)e2 * 512 * 512,
                                              wt_g0 + (size_t)e2 * 512 * 512, 512, 512);
  wT_bf16<<<dim3(4, 4), 256, 0, stream>>>(Wsk[1], wt_sk1, 128, 128);
  for (int e2 = 0; e2 < 5; e2++)
    wT_bf16<<<dim3(4, 16), 256, 0, stream>>>(Wg[1] + (size_t)e2 * 128 * 512,
                                             wt_g1 + (size_t)e2 * 512 * 128, 128, 512);

  auto run_layer = [&](const float* X, int Nf, int din, int li, float* fout,
                       const short* wt_sk, const short* wt_g) {
    const int Nsrc = (li == 0) ? 40000 : 20000;
    const int n_dst = (li == 0) ? 30000 : 10000;
    const int batch = (li == 0) ? 25000 : 8000;
    const int E = (li == 0) ? 200000 : 80000;

    gemm_mfma<<<dim3(1, cdiv(Nf, 128)), 512, 0, stream>>>(
        X, wt_sk, bsk[li], bufG, nullptr, Nf, din, 128);
    bn_partial<<<NSTATB, 128, 0, stream>>>(bufG, part, Nf);
    bn_finalize<<<128, 64, 0, stream>>>(part, NSTATB, Nf, stats);
    bn_apply<<<batch, 128, 0, stream>>>(bufG, stats, bng[li], bnb[li], temp,
                                        batch, 768, 1);

    for (int e2 = 0; e2 < 5; e2++) {
      const int* idx = nodes_idx[li] + (size_t)e2 * Nsrc;
      const int* src = edge_src[li] + (size_t)e2 * E;
      const int* dst = edge_dst[li] + (size_t)e2 * E;
      gemm_mfma<<<dim3(4, cdiv(Nsrc, 128)), 512, 0, stream>>>(
          X, wt_g + (size_t)e2 * din * 512, nullptr, bufG, idx, Nsrc, din, 512);
      att_scores<<<Nsrc, 256, 0, stream>>>(bufG, attS[li] + e2 * 512,
                                           attD[li] + e2 * 512, a_s, a_d, Nsrc, n_dst);
      build_starts<<<cdiv(E + 1, 256), 256, 0, stream>>>(dst, E, n_dst, starts);
      edge_logits<<<cdiv(E, 256), 256, 0, stream>>>(src, dst, a_s, a_d, logi, E);
      node_ms<<<cdiv(n_dst * 4, 256), 256, 0, stream>>>(logi, starts, ms, n_dst);
      edge_coef<<<cdiv(E, 256), 256, 0, stream>>>(logi, dst, ms, E);
      gat_aggregate<<<n_dst, 128, 0, stream>>>(bufG, logi, src, starts,
                                               bg[li] + e2 * 128, bufO, n_dst);
      bn_partial<<<NSTATB, 128, 0, stream>>>(bufO, part, n_dst);
      bn_finalize<<<128, 64, 0, stream>>>(part, NSTATB, n_dst, stats);
      bn_apply<<<batch, 128, 0, stream>>>(bufO, stats, bng[li] + (e2 + 1) * 128,
                                          bnb[li] + (e2 + 1) * 128,
                                          temp + (e2 + 1) * 128, batch, 768, 1);
    }

    pool_attn<<<batch, 128, 0, stream>>>(temp, wp[li], bp[li], bufO, batch);
    bn_partial<<<NSTATB, 128, 0, stream>>>(bufO, part, batch);
    bn_finalize<<<128, 64, 0, stream>>>(part, NSTATB, batch, stats);
    bn_apply<<<batch, 128, 0, stream>>>(bufO, stats, pg[li], pb[li], fout, batch,
                                        128, 0);
  };

  run_layer(feature, 100000, 512, 0, f0, wt_sk0, wt_g0);
  run_layer(f0, 25000, 128, 1, f1, wt_sk1, wt_g1);

  gemm_bias<<<dim3(cdiv(8000, 64), 2), 256, 0, stream>>>(f1, Wm1, bm1, bufG,
                                                         nullptr, 8000, 128, 128);
  bn_partial<<<NSTATB, 128, 0, stream>>>(bufG, part, 8000);
  bn_finalize<<<128, 64, 0, stream>>>(part, NSTATB, 8000, stats);
  bn_apply<<<8000, 128, 0, stream>>>(bufG, stats, mg, mb, bufH, 8000, 128, 2);
  gemm_bias<<<dim3(cdiv(8000, 64), 3), 256, 0, stream>>>(
      bufH, Wm2, bm2, (float*)d_out, nullptr, 8000, 128, 153);
}